// Round 9
// baseline (3301.357 us; speedup 1.0000x reference)
//
#include <hip/hip_runtime.h>
#include <hip/hip_bf16.h>
#include <cstdint>
#include <cstddef>

#define T_LEN 512
#define B_SZ  512
#define F_IN  64
#define H_DIM 128
#define NSTEP 8
#define T_CHUNK 128

typedef __attribute__((ext_vector_type(8))) short short8;
typedef __attribute__((ext_vector_type(4))) float f32x4;

__device__ __forceinline__ float fsig(float x) { return 1.0f / (1.0f + __expf(-x)); }
__device__ __forceinline__ float ftanh(float x) {
  float e = __expf(-2.0f * fabsf(x));
  float t = (1.0f - e) / (1.0f + e);
  return copysignf(t, x);
}
__device__ __forceinline__ unsigned short bf16hi(float x) {
  __hip_bfloat16 h = __float2bfloat16(x);
  return *(unsigned short*)&h;
}
__device__ __forceinline__ float bf2f(unsigned short u) {
  return __uint_as_float(((unsigned)u) << 16);
}
__device__ __forceinline__ float bflo(unsigned u) { return __uint_as_float(u << 16); }
__device__ __forceinline__ float bfhi(unsigned u) { return __uint_as_float(u & 0xffff0000u); }

// DPP cross-lane add within 16-lane rows (decoder scores)
template <int CTRL>
__device__ __forceinline__ float dpp_add(float v) {
  int p = __builtin_amdgcn_update_dpp(0, __float_as_int(v), CTRL, 0xF, 0xF, true);
  return v + __int_as_float(p);
}
__device__ __forceinline__ float row_sum16(float v) {
  v = dpp_add<0xB1>(v);
  v = dpp_add<0x4E>(v);
  v = dpp_add<0x124>(v);
  v = dpp_add<0x128>(v);
  return v;
}

// split 8 consecutive fp32 into bf16 hi/lo short8 fragments
__device__ __forceinline__ void split8(const float* p, short8& hi, short8& lo) {
  #pragma unroll
  for (int i = 0; i < 8; ++i) {
    const float v = p[i];
    const unsigned short h = bf16hi(v);
    hi[i] = (short)h;
    lo[i] = (short)bf16hi(v - bf2f(h));
  }
}

// -------------------------------------------------------------------------
// Split the 3 encoder w_ih matrices into bf16 hi/lo pairs (one-time prep).
// -------------------------------------------------------------------------
__global__ __launch_bounds__(256) void prep_split(
    const float* __restrict__ w0, const float* __restrict__ w1,
    const float* __restrict__ w2,
    unsigned short* __restrict__ hi, unsigned short* __restrict__ lo)
{
  const int i = blockIdx.x * 256 + threadIdx.x;
  if (i >= 122880) return;
  float v = (i < 24576) ? w0[i] : ((i < 73728) ? w1[i - 24576] : w2[i - 73728]);
  const unsigned short h = bf16hi(v);
  hi[i] = h;
  lo[i] = bf16hi(v - bf2f(h));
}

// -------------------------------------------------------------------------
// gx = A @ W^T + b_ih for one T-chunk, split-bf16 MFMA (R6 structure).
// -------------------------------------------------------------------------
__global__ __launch_bounds__(256) void gx_gemm(
    const float* __restrict__ x,
    const unsigned short* __restrict__ Ahi, const unsigned short* __restrict__ Alo,
    const unsigned short* __restrict__ Whi, const unsigned short* __restrict__ Wlo,
    const float* __restrict__ b_ih, float* __restrict__ gx,
    int t0, int k_dim, int is_layer0)
{
  __shared__ unsigned short Ah[128 * 40], Al[128 * 40];
  __shared__ unsigned short Bh[128 * 40], Bl[128 * 40];
  const int tid  = threadIdx.x;
  const int wave = tid >> 6, lane = tid & 63;
  const int quad = lane >> 4, l16 = lane & 15;
  const int m0 = blockIdx.x * 128;
  const int n0 = blockIdx.y * 128;
  const int wm = (wave & 1) * 64;
  const int wn = (wave >> 1) * 64;
  const size_t row0 = (size_t)t0 * B_SZ + m0;

  f32x4 acc[4][4];
  #pragma unroll
  for (int i = 0; i < 4; ++i)
    #pragma unroll
    for (int j = 0; j < 4; ++j) acc[i][j] = (f32x4){0.f, 0.f, 0.f, 0.f};

  float bias[4];
  #pragma unroll
  for (int nt = 0; nt < 4; ++nt) bias[nt] = b_ih[n0 + wn + nt * 16 + l16];

  for (int kc = 0; kc < k_dim; kc += 32) {
    __syncthreads();
    if (is_layer0) {
      #pragma unroll
      for (int g = tid; g < 1024; g += 256) {
        const int r = g >> 3, c4 = (g & 7) * 4;
        const int m = m0 + r;
        const int tg = t0 + (m >> 9), bb = m & 511;
        const float4 v = *(const float4*)&x[((size_t)bb * T_LEN + tg) * 64 + kc + c4];
        const unsigned short h0 = bf16hi(v.x), h1 = bf16hi(v.y),
                             h2 = bf16hi(v.z), h3 = bf16hi(v.w);
        ushort4 hv; hv.x = h0; hv.y = h1; hv.z = h2; hv.w = h3;
        ushort4 lv;
        lv.x = bf16hi(v.x - bf2f(h0)); lv.y = bf16hi(v.y - bf2f(h1));
        lv.z = bf16hi(v.z - bf2f(h2)); lv.w = bf16hi(v.w - bf2f(h3));
        *(ushort4*)&Ah[r * 40 + c4] = hv;
        *(ushort4*)&Al[r * 40 + c4] = lv;
      }
    } else {
      #pragma unroll
      for (int g = tid; g < 512; g += 256) {
        const int r = g >> 2, c8 = (g & 3) * 8;
        const size_t src = (row0 + r) * k_dim + kc + c8;
        *(uint4*)&Ah[r * 40 + c8] = *(const uint4*)&Ahi[src];
        *(uint4*)&Al[r * 40 + c8] = *(const uint4*)&Alo[src];
      }
    }
    #pragma unroll
    for (int g = tid; g < 512; g += 256) {
      const int r = g >> 2, c8 = (g & 3) * 8;
      const size_t src = (size_t)(n0 + r) * k_dim + kc + c8;
      *(uint4*)&Bh[r * 40 + c8] = *(const uint4*)&Whi[src];
      *(uint4*)&Bl[r * 40 + c8] = *(const uint4*)&Wlo[src];
    }
    __syncthreads();

    short8 ah[4], al[4], bh[4], bl[4];
    #pragma unroll
    for (int mt = 0; mt < 4; ++mt) {
      ah[mt] = *(const short8*)&Ah[(wm + mt * 16 + l16) * 40 + quad * 8];
      al[mt] = *(const short8*)&Al[(wm + mt * 16 + l16) * 40 + quad * 8];
    }
    #pragma unroll
    for (int nt = 0; nt < 4; ++nt) {
      bh[nt] = *(const short8*)&Bh[(wn + nt * 16 + l16) * 40 + quad * 8];
      bl[nt] = *(const short8*)&Bl[(wn + nt * 16 + l16) * 40 + quad * 8];
    }
    #pragma unroll
    for (int mt = 0; mt < 4; ++mt) {
      #pragma unroll
      for (int nt = 0; nt < 4; ++nt) {
        acc[mt][nt] = __builtin_amdgcn_mfma_f32_16x16x32_bf16(ah[mt], bh[nt], acc[mt][nt], 0, 0, 0);
        acc[mt][nt] = __builtin_amdgcn_mfma_f32_16x16x32_bf16(ah[mt], bl[nt], acc[mt][nt], 0, 0, 0);
        acc[mt][nt] = __builtin_amdgcn_mfma_f32_16x16x32_bf16(al[mt], bh[nt], acc[mt][nt], 0, 0, 0);
      }
    }
  }
  #pragma unroll
  for (int mt = 0; mt < 4; ++mt) {
    #pragma unroll
    for (int nt = 0; nt < 4; ++nt) {
      #pragma unroll
      for (int reg = 0; reg < 4; ++reg) {
        const int m = m0 + wm + mt * 16 + quad * 4 + reg;
        const int n = n0 + wn + nt * 16 + l16;
        gx[(size_t)m * 384 + n] = acc[mt][nt][reg] + bias[nt];
      }
    }
  }
}

// -------------------------------------------------------------------------
// MFMA recurrence with PREFETCH DISTANCE 2: at step t we issue the load of
// gx[t+2], compute MFMA, then stash gx[t+1] (loaded at step t-1 -> one full
// iteration of latency slack) into the alternate LDS buffer. This removes
// the exposed per-step global-load latency that bound R4-R8 (~2060 cyc/step).
// -------------------------------------------------------------------------
__global__ __launch_bounds__(512, 2) void rec_mfma(
    const float* __restrict__ gx,   // (T_CHUNK, B, 384), includes b_ih
    const float* __restrict__ w_hh, const float* __restrict__ b_hh,
    unsigned short* __restrict__ Hhi, unsigned short* __restrict__ Hlo,
    float* __restrict__ h_state,    // (B, 128)
    int t0, int chunk0)
{
  __shared__ unsigned short hsh[16 * 128];   // A-tile hi (rows 2-15 zero)
  __shared__ unsigned short hsl[16 * 128];   // A-tile lo
  __shared__ float ghs2[384 * 2];            // gh interleaved [n][row]
  __shared__ float gxs[2][2][384];
  __shared__ float bhl[384];

  const int tid  = threadIdx.x;
  const int wave = tid >> 6, lane = tid & 63;
  const int quad = lane >> 4, l16 = lane & 15;
  const int b0   = blockIdx.x * 2;

  // B-fragments (once per dispatch)
  short8 Bh[3][4], Bl[3][4];
  #pragma unroll
  for (int t = 0; t < 3; ++t) {
    const int n = (wave * 3 + t) * 16 + l16;
    #pragma unroll
    for (int c = 0; c < 4; ++c) {
      split8(&w_hh[(size_t)n * 128 + c * 32 + quad * 8], Bh[t][c], Bl[t][c]);
    }
  }
  if (tid < 384) bhl[tid] = b_hh[tid];
  for (int i = 256 + tid; i < 2048; i += 512) { hsh[i] = 0; hsl[i] = 0; }
  if (tid < 256) {
    const int rr = tid >> 7, c = tid & 127;
    const float h0 = chunk0 ? 0.0f : h_state[(size_t)(b0 + rr) * 128 + c];
    const unsigned short hh = bf16hi(h0);
    hsh[rr * 128 + c] = hh;
    hsl[rr * 128 + c] = bf16hi(h0 - bf2f(hh));
  }
  const int gr0 = (tid >= 384) ? 1 : 0;
  const int gi0 = tid - gr0 * 384;
  const int gi1 = tid + 128;                 // tid<256: covers row1 idx [128,384)
  // gxs[0] <- gx[0] (waited); gN <- gx[1] (in flight across iteration 0)
  gxs[0][gr0][gi0] = gx[(size_t)(b0 + gr0) * 384 + gi0];
  if (tid < 256) gxs[0][1][gi1] = gx[(size_t)(b0 + 1) * 384 + gi1];
  float gN0 = 0.0f, gN1 = 0.0f;
  if (1 < T_CHUNK) {
    gN0 = gx[((size_t)1 * B_SZ + b0 + gr0) * 384 + gi0];
    if (tid < 256) gN1 = gx[((size_t)1 * B_SZ + b0 + 1) * 384 + gi1];
  }
  __syncthreads();

  for (int tl = 0; tl < T_CHUNK; ++tl) {
    // issue load of gx[tl+2] (consumed at step tl+1's stash)
    float gM0 = 0.0f, gM1 = 0.0f;
    if (tl + 2 < T_CHUNK) {
      gM0 = gx[((size_t)(tl + 2) * B_SZ + b0 + gr0) * 384 + gi0];
      if (tid < 256)
        gM1 = gx[((size_t)(tl + 2) * B_SZ + b0 + 1) * 384 + gi1];
    }

    // A-fragments: lane row = l16 (rows>=2 read zeros)
    short8 Ahf[4], Alf[4];
    #pragma unroll
    for (int c = 0; c < 4; ++c) {
      const int ad = l16 * 128 + c * 32 + quad * 8;
      Ahf[c] = *(const short8*)&hsh[ad];
      Alf[c] = *(const short8*)&hsl[ad];
    }

    f32x4 acc[3];
    #pragma unroll
    for (int t = 0; t < 3; ++t) acc[t] = (f32x4){0.f, 0.f, 0.f, 0.f};
    #pragma unroll
    for (int c = 0; c < 4; ++c) {
      #pragma unroll
      for (int t = 0; t < 3; ++t) {
        acc[t] = __builtin_amdgcn_mfma_f32_16x16x32_bf16(Ahf[c], Bh[t][c], acc[t], 0, 0, 0);
        acc[t] = __builtin_amdgcn_mfma_f32_16x16x32_bf16(Ahf[c], Bl[t][c], acc[t], 0, 0, 0);
        acc[t] = __builtin_amdgcn_mfma_f32_16x16x32_bf16(Alf[c], Bh[t][c], acc[t], 0, 0, 0);
      }
    }
    if (quad == 0) {
      #pragma unroll
      for (int t = 0; t < 3; ++t) {
        const int n = (wave * 3 + t) * 16 + l16;
        *(float2*)&ghs2[n * 2] = make_float2(acc[t][0], acc[t][1]);
      }
    }
    // stash gx[tl+1] (loaded at step tl-1; ~1 iteration of slack)
    if (tl + 1 < T_CHUNK) {
      const int nb = (tl + 1) & 1;
      gxs[nb][gr0][gi0] = gN0;
      if (tid < 256) gxs[nb][1][gi1] = gN1;
    }
    __syncthreads();

    // gates (256 threads)
    if (tid < 256) {
      const int rr = tid >> 7, c = tid & 127;
      const float* gxp = gxs[tl & 1][rr];
      const float gh_r = ghs2[c * 2 + rr];
      const float gh_z = ghs2[(c + 128) * 2 + rr];
      const float gh_n = ghs2[(c + 256) * 2 + rr];
      const float h_old = bf2f(hsh[rr * 128 + c]) + bf2f(hsl[rr * 128 + c]);
      const float rg = fsig(gxp[c]       + gh_r + bhl[c]);
      const float zg = fsig(gxp[128 + c] + gh_z + bhl[128 + c]);
      const float ng = ftanh(gxp[256 + c] + rg * (gh_n + bhl[256 + c]));
      const float hn = (1.0f - zg) * ng + zg * h_old;
      const unsigned short hh = bf16hi(hn);
      const unsigned short hl = bf16hi(hn - bf2f(hh));
      hsh[rr * 128 + c] = hh;
      hsl[rr * 128 + c] = hl;
      const size_t ob = ((size_t)(t0 + tl) * B_SZ + (b0 + rr)) * 128 + c;
      Hhi[ob] = hh;
      Hlo[ob] = hl;
    }
    __syncthreads();

    gN0 = gM0;
    gN1 = gM1;
  }
  if (tid < 256) {
    const int rr = tid >> 7, c = tid & 127;
    h_state[(size_t)(b0 + rr) * 128 + c] =
        bf2f(hsh[rr * 128 + c]) + bf2f(hsl[rr * 128 + c]);
  }
}

// -------------------------------------------------------------------------
// keys = H @ aWk^T + abk, split-bf16 MFMA, output Khi (bf16 RNE) only.
// -------------------------------------------------------------------------
__global__ __launch_bounds__(256) void keys_gemm(
    const unsigned short* __restrict__ Ahi, const unsigned short* __restrict__ Alo,
    const float* __restrict__ aWk, const float* __restrict__ abk,
    unsigned short* __restrict__ Khi)
{
  __shared__ unsigned short Ah[64 * 40], Al[64 * 40];
  __shared__ unsigned short Bh[128 * 136], Bl[128 * 136];
  const int tid  = threadIdx.x;
  const int wave = tid >> 6, lane = tid & 63;
  const int quad = lane >> 4, l16 = lane & 15;
  const size_t m0 = (size_t)blockIdx.x * 64;

  for (int i = tid; i < 16384; i += 256) {
    const float v = aWk[i];
    const unsigned short h = bf16hi(v);
    const int r = i >> 7, k = i & 127;
    Bh[r * 136 + k] = h;
    Bl[r * 136 + k] = bf16hi(v - bf2f(h));
  }

  f32x4 acc[8];
  #pragma unroll
  for (int i = 0; i < 8; ++i) acc[i] = (f32x4){0.f, 0.f, 0.f, 0.f};
  float bias[8];
  #pragma unroll
  for (int nt = 0; nt < 8; ++nt) bias[nt] = abk[nt * 16 + l16];

  const int r = tid >> 2, c8 = (tid & 3) * 8;
  for (int kc = 0; kc < 128; kc += 32) {
    __syncthreads();
    const size_t src = (m0 + r) * 128 + kc + c8;
    *(uint4*)&Ah[r * 40 + c8] = *(const uint4*)&Ahi[src];
    *(uint4*)&Al[r * 40 + c8] = *(const uint4*)&Alo[src];
    __syncthreads();
    const short8 a_hi = *(const short8*)&Ah[(wave * 16 + l16) * 40 + quad * 8];
    const short8 a_lo = *(const short8*)&Al[(wave * 16 + l16) * 40 + quad * 8];
    #pragma unroll
    for (int nt = 0; nt < 8; ++nt) {
      const short8 b_hi = *(const short8*)&Bh[(nt * 16 + l16) * 136 + kc + quad * 8];
      const short8 b_lo = *(const short8*)&Bl[(nt * 16 + l16) * 136 + kc + quad * 8];
      acc[nt] = __builtin_amdgcn_mfma_f32_16x16x32_bf16(a_hi, b_hi, acc[nt], 0, 0, 0);
      acc[nt] = __builtin_amdgcn_mfma_f32_16x16x32_bf16(a_hi, b_lo, acc[nt], 0, 0, 0);
      acc[nt] = __builtin_amdgcn_mfma_f32_16x16x32_bf16(a_lo, b_hi, acc[nt], 0, 0, 0);
    }
  }
  #pragma unroll
  for (int nt = 0; nt < 8; ++nt) {
    #pragma unroll
    for (int reg = 0; reg < 4; ++reg) {
      const size_t m = m0 + wave * 16 + quad * 4 + reg;
      const int n = nt * 16 + l16;
      Khi[m * 128 + n] = bf16hi(acc[nt][reg] + bias[nt]);
    }
  }
}

// -------------------------------------------------------------------------
// Decoder (R7): one block per batch row, 512 threads, 8 steps in-kernel.
// -------------------------------------------------------------------------
__global__ __launch_bounds__(512) void decoder(
    const unsigned short* __restrict__ Hhi, const unsigned short* __restrict__ Hlo,
    const unsigned short* __restrict__ Khi,
    const float* __restrict__ aWq, const float* __restrict__ abq,
    const float* __restrict__ av,
    const float* __restrict__ dwih, const float* __restrict__ dwhh,
    const float* __restrict__ dbih, const float* __restrict__ dbhh,
    const float* __restrict__ lng, const float* __restrict__ lnb,
    const float* __restrict__ w1, const float* __restrict__ b1,
    const float* __restrict__ w2, const float* __restrict__ b2,
    float* __restrict__ out)
{
  __shared__ float h_s[128], q_s[128], av_s[128], s_s[512], w_s[512];
  __shared__ float part[8][128], u_s[256], gx_s[384], gh_s[384], y_s[128];
  __shared__ float red[16];
  const int b = blockIdx.x, tid = threadIdx.x;
  const int wave = tid >> 6, lane = tid & 63;
  const int tslot = lane >> 4, ks = lane & 15;

  if (tid < 128) {
    const size_t base = ((size_t)(T_LEN - 1) * B_SZ + b) * 128 + tid;
    h_s[tid] = bf2f(Hhi[base]) + bf2f(Hlo[base]);
    av_s[tid] = av[tid];
  }
  __syncthreads();

  for (int step = 0; step < NSTEP; ++step) {
    if (tid < 128) {
      float acc = abq[tid];
      const float* wr = &aWq[(size_t)tid * 128];
      #pragma unroll 8
      for (int k4 = 0; k4 < 32; ++k4) {
        const float4 hv = *(const float4*)&h_s[k4 * 4];
        const float4 wv = *(const float4*)&wr[k4 * 4];
        acc += hv.x * wv.x + hv.y * wv.y + hv.z * wv.z + hv.w * wv.w;
      }
      q_s[tid] = acc;
    }
    __syncthreads();
    #pragma unroll 2
    for (int it = 0; it < 16; ++it) {
      const int t = it * 32 + wave * 4 + tslot;
      const size_t kb = ((size_t)t * B_SZ + b) * 128 + ks * 8;
      const uint4 uh = *(const uint4*)&Khi[kb];
      const float4 q0 = *(const float4*)&q_s[ks * 8];
      const float4 q1 = *(const float4*)&q_s[ks * 8 + 4];
      const float4 a0 = *(const float4*)&av_s[ks * 8];
      const float4 a1 = *(const float4*)&av_s[ks * 8 + 4];
      float acc = ftanh(bflo(uh.x) + q0.x) * a0.x + ftanh(bfhi(uh.x) + q0.y) * a0.y
                + ftanh(bflo(uh.y) + q0.z) * a0.z + ftanh(bfhi(uh.y) + q0.w) * a0.w
                + ftanh(bflo(uh.z) + q1.x) * a1.x + ftanh(bfhi(uh.z) + q1.y) * a1.y
                + ftanh(bflo(uh.w) + q1.z) * a1.z + ftanh(bfhi(uh.w) + q1.w) * a1.w;
      acc = row_sum16(acc);
      if (ks == 0) s_s[t] = acc;
    }
    __syncthreads();
    {
      const float sv = s_s[tid];
      float mx = sv;
      #pragma unroll
      for (int o = 32; o; o >>= 1) mx = fmaxf(mx, __shfl_xor(mx, o, 64));
      if (lane == 0) red[wave] = mx;
      __syncthreads();
      mx = red[0];
      #pragma unroll
      for (int i = 1; i < 8; ++i) mx = fmaxf(mx, red[i]);
      const float e = __expf(sv - mx);
      float sm = e;
      #pragma unroll
      for (int o = 32; o; o >>= 1) sm += __shfl_xor(sm, o, 64);
      if (lane == 0) red[8 + wave] = sm;
      __syncthreads();
      float tot = red[8];
      #pragma unroll
      for (int i = 1; i < 8; ++i) tot += red[8 + i];
      w_s[tid] = e / tot;
    }
    __syncthreads();
    {
      const int th = tid >> 6;
      const int c2 = (tid & 63) * 2;
      float acc0 = 0.0f, acc1 = 0.0f;
      #pragma unroll 4
      for (int q = 0; q < 64; ++q) {
        const int t = th * 64 + q;
        const unsigned u = *(const unsigned*)&Hhi[((size_t)t * B_SZ + b) * 128 + c2];
        const float wt = w_s[t];
        acc0 += wt * bflo(u);
        acc1 += wt * bfhi(u);
      }
      part[th][c2] = acc0;
      part[th][c2 + 1] = acc1;
    }
    __syncthreads();
    if (tid < 128) {
      float s = part[0][tid];
      #pragma unroll
      for (int i = 1; i < 8; ++i) s += part[i][tid];
      u_s[tid] = s;
      u_s[128 + tid] = h_s[tid];
    }
    __syncthreads();
    if (tid < 384) {
      const int j = tid;
      float gxv = dbih[j], ghv = dbhh[j];
      const float* wxr = &dwih[(size_t)j * 256];
      const float* whr = &dwhh[(size_t)j * 128];
      #pragma unroll 8
      for (int k4 = 0; k4 < 64; ++k4) {
        const float4 uv = *(const float4*)&u_s[k4 * 4];
        const float4 wv = *(const float4*)&wxr[k4 * 4];
        gxv += uv.x * wv.x + uv.y * wv.y + uv.z * wv.z + uv.w * wv.w;
      }
      #pragma unroll 8
      for (int k4 = 0; k4 < 32; ++k4) {
        const float4 hv = *(const float4*)&h_s[k4 * 4];
        const float4 wv = *(const float4*)&whr[k4 * 4];
        ghv += hv.x * wv.x + hv.y * wv.y + hv.z * wv.z + hv.w * wv.w;
      }
      gx_s[j] = gxv; gh_s[j] = ghv;
    }
    __syncthreads();
    if (tid < 128) {
      const float r = fsig(gx_s[tid] + gh_s[tid]);
      const float z = fsig(gx_s[128 + tid] + gh_s[128 + tid]);
      const float n = ftanh(gx_s[256 + tid] + r * gh_s[256 + tid]);
      const float hn = (1.0f - z) * n + z * h_s[tid];
      h_s[tid] = hn;
      float s1 = hn, s2 = hn * hn;
      #pragma unroll
      for (int o = 32; o; o >>= 1) { s1 += __shfl_xor(s1, o, 64); s2 += __shfl_xor(s2, o, 64); }
      if ((tid & 63) == 0) { red[tid >> 6] = s1; red[4 + (tid >> 6)] = s2; }
    }
    __syncthreads();
    if (tid < 128) {
      const float hn  = h_s[tid];
      const float mu  = (red[0] + red[1]) * (1.0f / 128.0f);
      const float var = (red[4] + red[5]) * (1.0f / 128.0f) - mu * mu;
      y_s[tid] = (hn - mu) / sqrtf(var + 1e-5f) * lng[tid] + lnb[tid];
    }
    __syncthreads();
    if (tid < 64) {
      float acc = b1[tid];
      const float* wr = &w1[(size_t)tid * 128];
      #pragma unroll 8
      for (int k4 = 0; k4 < 32; ++k4) {
        const float4 yv = *(const float4*)&y_s[k4 * 4];
        const float4 wv = *(const float4*)&wr[k4 * 4];
        acc += yv.x * wv.x + yv.y * wv.y + yv.z * wv.z + yv.w * wv.w;
      }
      acc = fmaxf(acc, 0.0f);
      float v = acc * w2[tid];
      #pragma unroll
      for (int o = 32; o; o >>= 1) v += __shfl_xor(v, o, 64);
      if (tid == 0) out[(size_t)b * NSTEP + step] = v + b2[0];
    }
    __syncthreads();
  }
}

// -------------------------------------------------------------------------
extern "C" void kernel_launch(void* const* d_in, const int* in_sizes, int n_in,
                              void* d_out, int out_size, void* d_ws, size_t ws_size,
                              hipStream_t stream)
{
  (void)in_sizes; (void)n_in; (void)out_size; (void)ws_size;
  const float* x    = (const float*)d_in[0];
  const float* ewih[3] = {(const float*)d_in[1], (const float*)d_in[5], (const float*)d_in[9]};
  const float* ewhh[3] = {(const float*)d_in[2], (const float*)d_in[6], (const float*)d_in[10]};
  const float* ebih[3] = {(const float*)d_in[3], (const float*)d_in[7], (const float*)d_in[11]};
  const float* ebhh[3] = {(const float*)d_in[4], (const float*)d_in[8], (const float*)d_in[12]};
  const float* aWq  = (const float*)d_in[13];
  const float* abq  = (const float*)d_in[14];
  const float* aWk  = (const float*)d_in[15];
  const float* abk  = (const float*)d_in[16];
  const float* av   = (const float*)d_in[17];
  const float* dwih = (const float*)d_in[18];
  const float* dwhh = (const float*)d_in[19];
  const float* dbih = (const float*)d_in[20];
  const float* dbhh = (const float*)d_in[21];
  const float* lng  = (const float*)d_in[22];
  const float* lnb  = (const float*)d_in[23];
  const float* w1   = (const float*)d_in[24];
  const float* b1   = (const float*)d_in[25];
  const float* w2   = (const float*)d_in[26];
  const float* b2   = (const float*)d_in[27];

  const size_t HN = (size_t)T_LEN * B_SZ * H_DIM;               // 33,554,432 elems
  unsigned short* Hhi = (unsigned short*)d_ws;                  // 64 MiB (T,B,H)
  unsigned short* Hlo = Hhi + HN;                               // 64 MiB
  float* regionC = (float*)(Hlo + HN);                          // 128 MiB
  float* gxc     = regionC;                                     // 96 MiB
  float* h_state = regionC + 25165824;
  unsigned short* Whi = (unsigned short*)(h_state + 65536);
  unsigned short* Wlo = Whi + 122880;
  unsigned short* Khi = (unsigned short*)regionC;               // decode: 64 MiB

  prep_split<<<dim3(480), dim3(256), 0, stream>>>(ewih[0], ewih[1], ewih[2], Whi, Wlo);

  const int koff[3] = {0, 24576, 73728};
  const int kdim[3] = {64, 128, 128};
  for (int l = 0; l < 3; ++l) {
    for (int c = 0; c < 4; ++c) {
      const int t0 = c * T_CHUNK;
      gx_gemm<<<dim3(512, 3), dim3(256), 0, stream>>>(
          x, Hhi, Hlo, Whi + koff[l], Wlo + koff[l], ebih[l],
          gxc, t0, kdim[l], (l == 0) ? 1 : 0);
      rec_mfma<<<dim3(256), dim3(512), 0, stream>>>(
          gxc, ewhh[l], ebhh[l], Hhi, Hlo, h_state, t0, (c == 0) ? 1 : 0);
    }
  }

  keys_gemm<<<dim3(4096), dim3(256), 0, stream>>>(Hhi, Hlo, aWk, abk, Khi);
  decoder<<<dim3(512), dim3(512), 0, stream>>>(
      Hhi, Hlo, Khi, aWq, abq, av, dwih, dwhh, dbih, dbhh,
      lng, lnb, w1, b1, w2, b2, (float*)d_out);
}

// Round 10
// 3113.832 us; speedup vs baseline: 1.0602x; 1.0602x over previous
//
#include <hip/hip_runtime.h>
#include <hip/hip_bf16.h>
#include <cstdint>
#include <cstddef>

#define T_LEN 512
#define B_SZ  512
#define F_IN  64
#define H_DIM 128
#define NSTEP 8
#define T_CHUNK 128

typedef __attribute__((ext_vector_type(8))) short short8;
typedef __attribute__((ext_vector_type(4))) float f32x4;

__device__ __forceinline__ float fsig(float x) { return 1.0f / (1.0f + __expf(-x)); }
__device__ __forceinline__ float ftanh(float x) {
  float e = __expf(-2.0f * fabsf(x));
  float t = (1.0f - e) / (1.0f + e);
  return copysignf(t, x);
}
__device__ __forceinline__ unsigned short bf16hi(float x) {
  __hip_bfloat16 h = __float2bfloat16(x);
  return *(unsigned short*)&h;
}
__device__ __forceinline__ float bf2f(unsigned short u) {
  return __uint_as_float(((unsigned)u) << 16);
}
__device__ __forceinline__ float bflo(unsigned u) { return __uint_as_float(u << 16); }
__device__ __forceinline__ float bfhi(unsigned u) { return __uint_as_float(u & 0xffff0000u); }

// DPP cross-lane add within 16-lane rows (decoder scores)
template <int CTRL>
__device__ __forceinline__ float dpp_add(float v) {
  int p = __builtin_amdgcn_update_dpp(0, __float_as_int(v), CTRL, 0xF, 0xF, true);
  return v + __int_as_float(p);
}
__device__ __forceinline__ float row_sum16(float v) {
  v = dpp_add<0xB1>(v);
  v = dpp_add<0x4E>(v);
  v = dpp_add<0x124>(v);
  v = dpp_add<0x128>(v);
  return v;
}

// split 8 consecutive fp32 into bf16 hi/lo short8 fragments
__device__ __forceinline__ void split8(const float* p, short8& hi, short8& lo) {
  #pragma unroll
  for (int i = 0; i < 8; ++i) {
    const float v = p[i];
    const unsigned short h = bf16hi(v);
    hi[i] = (short)h;
    lo[i] = (short)bf16hi(v - bf2f(h));
  }
}

// -------------------------------------------------------------------------
// Split the 3 encoder w_ih matrices into bf16 hi/lo pairs (one-time prep).
// -------------------------------------------------------------------------
__global__ __launch_bounds__(256) void prep_split(
    const float* __restrict__ w0, const float* __restrict__ w1,
    const float* __restrict__ w2,
    unsigned short* __restrict__ hi, unsigned short* __restrict__ lo)
{
  const int i = blockIdx.x * 256 + threadIdx.x;
  if (i >= 122880) return;
  float v = (i < 24576) ? w0[i] : ((i < 73728) ? w1[i - 24576] : w2[i - 73728]);
  const unsigned short h = bf16hi(v);
  hi[i] = h;
  lo[i] = bf16hi(v - bf2f(h));
}

// -------------------------------------------------------------------------
// gx = A @ W^T + b_ih for one T-chunk, split-bf16 MFMA (R6 structure).
// -------------------------------------------------------------------------
__global__ __launch_bounds__(256) void gx_gemm(
    const float* __restrict__ x,
    const unsigned short* __restrict__ Ahi, const unsigned short* __restrict__ Alo,
    const unsigned short* __restrict__ Whi, const unsigned short* __restrict__ Wlo,
    const float* __restrict__ b_ih, float* __restrict__ gx,
    int t0, int k_dim, int is_layer0)
{
  __shared__ unsigned short Ah[128 * 40], Al[128 * 40];
  __shared__ unsigned short Bh[128 * 40], Bl[128 * 40];
  const int tid  = threadIdx.x;
  const int wave = tid >> 6, lane = tid & 63;
  const int quad = lane >> 4, l16 = lane & 15;
  const int m0 = blockIdx.x * 128;
  const int n0 = blockIdx.y * 128;
  const int wm = (wave & 1) * 64;
  const int wn = (wave >> 1) * 64;
  const size_t row0 = (size_t)t0 * B_SZ + m0;

  f32x4 acc[4][4];
  #pragma unroll
  for (int i = 0; i < 4; ++i)
    #pragma unroll
    for (int j = 0; j < 4; ++j) acc[i][j] = (f32x4){0.f, 0.f, 0.f, 0.f};

  float bias[4];
  #pragma unroll
  for (int nt = 0; nt < 4; ++nt) bias[nt] = b_ih[n0 + wn + nt * 16 + l16];

  for (int kc = 0; kc < k_dim; kc += 32) {
    __syncthreads();
    if (is_layer0) {
      #pragma unroll
      for (int g = tid; g < 1024; g += 256) {
        const int r = g >> 3, c4 = (g & 7) * 4;
        const int m = m0 + r;
        const int tg = t0 + (m >> 9), bb = m & 511;
        const float4 v = *(const float4*)&x[((size_t)bb * T_LEN + tg) * 64 + kc + c4];
        const unsigned short h0 = bf16hi(v.x), h1 = bf16hi(v.y),
                             h2 = bf16hi(v.z), h3 = bf16hi(v.w);
        ushort4 hv; hv.x = h0; hv.y = h1; hv.z = h2; hv.w = h3;
        ushort4 lv;
        lv.x = bf16hi(v.x - bf2f(h0)); lv.y = bf16hi(v.y - bf2f(h1));
        lv.z = bf16hi(v.z - bf2f(h2)); lv.w = bf16hi(v.w - bf2f(h3));
        *(ushort4*)&Ah[r * 40 + c4] = hv;
        *(ushort4*)&Al[r * 40 + c4] = lv;
      }
    } else {
      #pragma unroll
      for (int g = tid; g < 512; g += 256) {
        const int r = g >> 2, c8 = (g & 3) * 8;
        const size_t src = (row0 + r) * k_dim + kc + c8;
        *(uint4*)&Ah[r * 40 + c8] = *(const uint4*)&Ahi[src];
        *(uint4*)&Al[r * 40 + c8] = *(const uint4*)&Alo[src];
      }
    }
    #pragma unroll
    for (int g = tid; g < 512; g += 256) {
      const int r = g >> 2, c8 = (g & 3) * 8;
      const size_t src = (size_t)(n0 + r) * k_dim + kc + c8;
      *(uint4*)&Bh[r * 40 + c8] = *(const uint4*)&Whi[src];
      *(uint4*)&Bl[r * 40 + c8] = *(const uint4*)&Wlo[src];
    }
    __syncthreads();

    short8 ah[4], al[4], bh[4], bl[4];
    #pragma unroll
    for (int mt = 0; mt < 4; ++mt) {
      ah[mt] = *(const short8*)&Ah[(wm + mt * 16 + l16) * 40 + quad * 8];
      al[mt] = *(const short8*)&Al[(wm + mt * 16 + l16) * 40 + quad * 8];
    }
    #pragma unroll
    for (int nt = 0; nt < 4; ++nt) {
      bh[nt] = *(const short8*)&Bh[(wn + nt * 16 + l16) * 40 + quad * 8];
      bl[nt] = *(const short8*)&Bl[(wn + nt * 16 + l16) * 40 + quad * 8];
    }
    #pragma unroll
    for (int mt = 0; mt < 4; ++mt) {
      #pragma unroll
      for (int nt = 0; nt < 4; ++nt) {
        acc[mt][nt] = __builtin_amdgcn_mfma_f32_16x16x32_bf16(ah[mt], bh[nt], acc[mt][nt], 0, 0, 0);
        acc[mt][nt] = __builtin_amdgcn_mfma_f32_16x16x32_bf16(ah[mt], bl[nt], acc[mt][nt], 0, 0, 0);
        acc[mt][nt] = __builtin_amdgcn_mfma_f32_16x16x32_bf16(al[mt], bh[nt], acc[mt][nt], 0, 0, 0);
      }
    }
  }
  #pragma unroll
  for (int mt = 0; mt < 4; ++mt) {
    #pragma unroll
    for (int nt = 0; nt < 4; ++nt) {
      #pragma unroll
      for (int reg = 0; reg < 4; ++reg) {
        const int m = m0 + wm + mt * 16 + quad * 4 + reg;
        const int n = n0 + wn + nt * 16 + l16;
        gx[(size_t)m * 384 + n] = acc[mt][nt][reg] + bias[nt];
      }
    }
  }
}

// -------------------------------------------------------------------------
// Single-barrier MFMA recurrence. 256 blocks x 2 batch rows, 512 thr/8 waves.
// Wave w computes the 16-wide n-tiles at n = c, 128+c, 256+c for channels
// c in [16w,16w+16): after MFMA, quad-0 lane l16 holds gh_r/gh_z/gh_n for
// channel c=16w+l16 rows 0,1 IN-REGISTER (C-layout regs 0,1). Gates compute
// in-lane: no gh LDS round-trip, no second barrier. h_old / b_hh / gx all
// in registers (gx: 64-B coalesced per-gate-lane loads, dist-2 pipeline).
// LDS = double-buffered 2x128 split-bf16 h tile only. A-operand rows >=2
// feed only unused C rows -> lanes l16>=2 carry zeros (masked LDS reads).
// -------------------------------------------------------------------------
__global__ __launch_bounds__(512, 1) void rec_mfma(
    const float* __restrict__ gx,   // (T_CHUNK, B, 384), includes b_ih
    const float* __restrict__ w_hh, const float* __restrict__ b_hh,
    unsigned short* __restrict__ Hhi, unsigned short* __restrict__ Hlo,
    float* __restrict__ h_state,    // (B, 128)
    int t0, int chunk0)
{
  __shared__ unsigned short hsh[2][256];   // [buf][row*128 + c]
  __shared__ unsigned short hsl[2][256];

  const int tid  = threadIdx.x;
  const int wave = tid >> 6, lane = tid & 63;
  const int quad = lane >> 4, l16 = lane & 15;
  const int b0   = blockIdx.x * 2;
  const int c    = wave * 16 + l16;        // owned channel (quad-0 lanes)

  // B-fragments: gate g tile base n = g*128 + 16w; lane n = g*128 + c,
  // k = ck*32 + quad*8 (8 consecutive). 24 short8 hi + lo = 96 VGPR.
  short8 Bh[3][4], Bl[3][4];
  #pragma unroll
  for (int g = 0; g < 3; ++g) {
    #pragma unroll
    for (int ck = 0; ck < 4; ++ck)
      split8(&w_hh[(size_t)(g * 128 + c) * 128 + ck * 32 + quad * 8],
             Bh[g][ck], Bl[g][ck]);
  }

  float bias_r = 0.f, bias_z = 0.f, bias_n = 0.f, h0 = 0.f, h1 = 0.f;
  float gc[6], g1[6];
  if (quad == 0) {
    bias_r = b_hh[c]; bias_z = b_hh[c + 128]; bias_n = b_hh[c + 256];
    if (!chunk0) {
      h0 = h_state[(size_t)b0 * 128 + c];
      h1 = h_state[(size_t)(b0 + 1) * 128 + c];
    }
    const unsigned short hh0 = bf16hi(h0), hh1 = bf16hi(h1);
    hsh[0][c] = hh0;        hsh[0][128 + c] = hh1;
    hsl[0][c] = bf16hi(h0 - bf2f(hh0));
    hsl[0][128 + c] = bf16hi(h1 - bf2f(hh1));
    #pragma unroll
    for (int r = 0; r < 2; ++r)
      #pragma unroll
      for (int g = 0; g < 3; ++g) {
        gc[r * 3 + g] = gx[(size_t)(b0 + r) * 384 + g * 128 + c];
        g1[r * 3 + g] = (T_CHUNK > 1)
            ? gx[((size_t)1 * B_SZ + b0 + r) * 384 + g * 128 + c] : 0.0f;
      }
  } else {
    #pragma unroll
    for (int i = 0; i < 6; ++i) { gc[i] = 0.f; g1[i] = 0.f; }
  }
  __syncthreads();

  for (int tl = 0; tl < T_CHUNK; ++tl) {
    // issue gx[tl+2] loads (consumed 2 iterations later -> full slack)
    float g2[6];
    #pragma unroll
    for (int i = 0; i < 6; ++i) g2[i] = 0.f;
    if (quad == 0 && tl + 2 < T_CHUNK) {
      #pragma unroll
      for (int r = 0; r < 2; ++r)
        #pragma unroll
        for (int g = 0; g < 3; ++g)
          g2[r * 3 + g] = gx[((size_t)(tl + 2) * B_SZ + b0 + r) * 384 + g * 128 + c];
    }

    // A-fragments: lane row = l16; rows >=2 are zeros (their C rows unused)
    short8 Ahf[4], Alf[4];
    if (l16 < 2) {
      #pragma unroll
      for (int ck = 0; ck < 4; ++ck) {
        const int ad = l16 * 128 + ck * 32 + quad * 8;
        Ahf[ck] = *(const short8*)&hsh[tl & 1][ad];
        Alf[ck] = *(const short8*)&hsl[tl & 1][ad];
      }
    } else {
      #pragma unroll
      for (int ck = 0; ck < 4; ++ck) {
        Ahf[ck] = (short8){0, 0, 0, 0, 0, 0, 0, 0};
        Alf[ck] = (short8){0, 0, 0, 0, 0, 0, 0, 0};
      }
    }

    // 36 MFMA/wave; 2 partial accumulators per gate halve the dep chain
    f32x4 acc[3][2];
    #pragma unroll
    for (int g = 0; g < 3; ++g) {
      acc[g][0] = (f32x4){0.f, 0.f, 0.f, 0.f};
      acc[g][1] = (f32x4){0.f, 0.f, 0.f, 0.f};
    }
    #pragma unroll
    for (int ck = 0; ck < 4; ++ck) {
      const int p = ck >> 1;
      #pragma unroll
      for (int g = 0; g < 3; ++g) {
        acc[g][p] = __builtin_amdgcn_mfma_f32_16x16x32_bf16(Ahf[ck], Bh[g][ck], acc[g][p], 0, 0, 0);
        acc[g][p] = __builtin_amdgcn_mfma_f32_16x16x32_bf16(Ahf[ck], Bl[g][ck], acc[g][p], 0, 0, 0);
        acc[g][p] = __builtin_amdgcn_mfma_f32_16x16x32_bf16(Alf[ck], Bh[g][ck], acc[g][p], 0, 0, 0);
      }
    }

    // in-lane gates (quad-0): gh for channel c rows 0,1 are regs 0,1
    if (quad == 0) {
      const float ghr0 = acc[0][0][0] + acc[0][1][0];
      const float ghr1 = acc[0][0][1] + acc[0][1][1];
      const float ghz0 = acc[1][0][0] + acc[1][1][0];
      const float ghz1 = acc[1][0][1] + acc[1][1][1];
      const float ghn0 = acc[2][0][0] + acc[2][1][0];
      const float ghn1 = acc[2][0][1] + acc[2][1][1];
      const float r0 = fsig(gc[0] + ghr0 + bias_r);
      const float z0 = fsig(gc[1] + ghz0 + bias_z);
      const float nv0 = ftanh(gc[2] + r0 * (ghn0 + bias_n));
      const float hn0 = (1.0f - z0) * nv0 + z0 * h0;
      const float r1 = fsig(gc[3] + ghr1 + bias_r);
      const float z1 = fsig(gc[4] + ghz1 + bias_z);
      const float nv1 = ftanh(gc[5] + r1 * (ghn1 + bias_n));
      const float hn1 = (1.0f - z1) * nv1 + z1 * h1;
      h0 = hn0; h1 = hn1;
      const int nb = (tl + 1) & 1;
      const unsigned short hh0 = bf16hi(hn0), hh1 = bf16hi(hn1);
      const unsigned short hl0 = bf16hi(hn0 - bf2f(hh0));
      const unsigned short hl1 = bf16hi(hn1 - bf2f(hh1));
      hsh[nb][c] = hh0;       hsh[nb][128 + c] = hh1;
      hsl[nb][c] = hl0;       hsl[nb][128 + c] = hl1;
      const size_t ob = ((size_t)(t0 + tl) * B_SZ + b0) * 128 + c;
      Hhi[ob] = hh0;        Hlo[ob] = hl0;
      Hhi[ob + 128] = hh1;  Hlo[ob + 128] = hl1;
    }
    __syncthreads();
    #pragma unroll
    for (int i = 0; i < 6; ++i) { gc[i] = g1[i]; g1[i] = g2[i]; }
  }
  if (quad == 0) {
    h_state[(size_t)b0 * 128 + c] = h0;
    h_state[(size_t)(b0 + 1) * 128 + c] = h1;
  }
}

// -------------------------------------------------------------------------
// keys = H @ aWk^T + abk, split-bf16 MFMA, output Khi (bf16 RNE) only.
// -------------------------------------------------------------------------
__global__ __launch_bounds__(256) void keys_gemm(
    const unsigned short* __restrict__ Ahi, const unsigned short* __restrict__ Alo,
    const float* __restrict__ aWk, const float* __restrict__ abk,
    unsigned short* __restrict__ Khi)
{
  __shared__ unsigned short Ah[64 * 40], Al[64 * 40];
  __shared__ unsigned short Bh[128 * 136], Bl[128 * 136];
  const int tid  = threadIdx.x;
  const int wave = tid >> 6, lane = tid & 63;
  const int quad = lane >> 4, l16 = lane & 15;
  const size_t m0 = (size_t)blockIdx.x * 64;

  for (int i = tid; i < 16384; i += 256) {
    const float v = aWk[i];
    const unsigned short h = bf16hi(v);
    const int r = i >> 7, k = i & 127;
    Bh[r * 136 + k] = h;
    Bl[r * 136 + k] = bf16hi(v - bf2f(h));
  }

  f32x4 acc[8];
  #pragma unroll
  for (int i = 0; i < 8; ++i) acc[i] = (f32x4){0.f, 0.f, 0.f, 0.f};
  float bias[8];
  #pragma unroll
  for (int nt = 0; nt < 8; ++nt) bias[nt] = abk[nt * 16 + l16];

  const int r = tid >> 2, c8 = (tid & 3) * 8;
  for (int kc = 0; kc < 128; kc += 32) {
    __syncthreads();
    const size_t src = (m0 + r) * 128 + kc + c8;
    *(uint4*)&Ah[r * 40 + c8] = *(const uint4*)&Ahi[src];
    *(uint4*)&Al[r * 40 + c8] = *(const uint4*)&Alo[src];
    __syncthreads();
    const short8 a_hi = *(const short8*)&Ah[(wave * 16 + l16) * 40 + quad * 8];
    const short8 a_lo = *(const short8*)&Al[(wave * 16 + l16) * 40 + quad * 8];
    #pragma unroll
    for (int nt = 0; nt < 8; ++nt) {
      const short8 b_hi = *(const short8*)&Bh[(nt * 16 + l16) * 136 + kc + quad * 8];
      const short8 b_lo = *(const short8*)&Bl[(nt * 16 + l16) * 136 + kc + quad * 8];
      acc[nt] = __builtin_amdgcn_mfma_f32_16x16x32_bf16(a_hi, b_hi, acc[nt], 0, 0, 0);
      acc[nt] = __builtin_amdgcn_mfma_f32_16x16x32_bf16(a_hi, b_lo, acc[nt], 0, 0, 0);
      acc[nt] = __builtin_amdgcn_mfma_f32_16x16x32_bf16(a_lo, b_hi, acc[nt], 0, 0, 0);
    }
  }
  #pragma unroll
  for (int nt = 0; nt < 8; ++nt) {
    #pragma unroll
    for (int reg = 0; reg < 4; ++reg) {
      const size_t m = m0 + wave * 16 + quad * 4 + reg;
      const int n = nt * 16 + l16;
      Khi[m * 128 + n] = bf16hi(acc[nt][reg] + bias[nt]);
    }
  }
}

// -------------------------------------------------------------------------
// Decoder (R7): one block per batch row, 512 threads, 8 steps in-kernel.
// -------------------------------------------------------------------------
__global__ __launch_bounds__(512) void decoder(
    const unsigned short* __restrict__ Hhi, const unsigned short* __restrict__ Hlo,
    const unsigned short* __restrict__ Khi,
    const float* __restrict__ aWq, const float* __restrict__ abq,
    const float* __restrict__ av,
    const float* __restrict__ dwih, const float* __restrict__ dwhh,
    const float* __restrict__ dbih, const float* __restrict__ dbhh,
    const float* __restrict__ lng, const float* __restrict__ lnb,
    const float* __restrict__ w1, const float* __restrict__ b1,
    const float* __restrict__ w2, const float* __restrict__ b2,
    float* __restrict__ out)
{
  __shared__ float h_s[128], q_s[128], av_s[128], s_s[512], w_s[512];
  __shared__ float part[8][128], u_s[256], gx_s[384], gh_s[384], y_s[128];
  __shared__ float red[16];
  const int b = blockIdx.x, tid = threadIdx.x;
  const int wave = tid >> 6, lane = tid & 63;
  const int tslot = lane >> 4, ks = lane & 15;

  if (tid < 128) {
    const size_t base = ((size_t)(T_LEN - 1) * B_SZ + b) * 128 + tid;
    h_s[tid] = bf2f(Hhi[base]) + bf2f(Hlo[base]);
    av_s[tid] = av[tid];
  }
  __syncthreads();

  for (int step = 0; step < NSTEP; ++step) {
    if (tid < 128) {
      float acc = abq[tid];
      const float* wr = &aWq[(size_t)tid * 128];
      #pragma unroll 8
      for (int k4 = 0; k4 < 32; ++k4) {
        const float4 hv = *(const float4*)&h_s[k4 * 4];
        const float4 wv = *(const float4*)&wr[k4 * 4];
        acc += hv.x * wv.x + hv.y * wv.y + hv.z * wv.z + hv.w * wv.w;
      }
      q_s[tid] = acc;
    }
    __syncthreads();
    #pragma unroll 2
    for (int it = 0; it < 16; ++it) {
      const int t = it * 32 + wave * 4 + tslot;
      const size_t kb = ((size_t)t * B_SZ + b) * 128 + ks * 8;
      const uint4 uh = *(const uint4*)&Khi[kb];
      const float4 q0 = *(const float4*)&q_s[ks * 8];
      const float4 q1 = *(const float4*)&q_s[ks * 8 + 4];
      const float4 a0 = *(const float4*)&av_s[ks * 8];
      const float4 a1 = *(const float4*)&av_s[ks * 8 + 4];
      float acc = ftanh(bflo(uh.x) + q0.x) * a0.x + ftanh(bfhi(uh.x) + q0.y) * a0.y
                + ftanh(bflo(uh.y) + q0.z) * a0.z + ftanh(bfhi(uh.y) + q0.w) * a0.w
                + ftanh(bflo(uh.z) + q1.x) * a1.x + ftanh(bfhi(uh.z) + q1.y) * a1.y
                + ftanh(bflo(uh.w) + q1.z) * a1.z + ftanh(bfhi(uh.w) + q1.w) * a1.w;
      acc = row_sum16(acc);
      if (ks == 0) s_s[t] = acc;
    }
    __syncthreads();
    {
      const float sv = s_s[tid];
      float mx = sv;
      #pragma unroll
      for (int o = 32; o; o >>= 1) mx = fmaxf(mx, __shfl_xor(mx, o, 64));
      if (lane == 0) red[wave] = mx;
      __syncthreads();
      mx = red[0];
      #pragma unroll
      for (int i = 1; i < 8; ++i) mx = fmaxf(mx, red[i]);
      const float e = __expf(sv - mx);
      float sm = e;
      #pragma unroll
      for (int o = 32; o; o >>= 1) sm += __shfl_xor(sm, o, 64);
      if (lane == 0) red[8 + wave] = sm;
      __syncthreads();
      float tot = red[8];
      #pragma unroll
      for (int i = 1; i < 8; ++i) tot += red[8 + i];
      w_s[tid] = e / tot;
    }
    __syncthreads();
    {
      const int th = tid >> 6;
      const int c2 = (tid & 63) * 2;
      float acc0 = 0.0f, acc1 = 0.0f;
      #pragma unroll 4
      for (int q = 0; q < 64; ++q) {
        const int t = th * 64 + q;
        const unsigned u = *(const unsigned*)&Hhi[((size_t)t * B_SZ + b) * 128 + c2];
        const float wt = w_s[t];
        acc0 += wt * bflo(u);
        acc1 += wt * bfhi(u);
      }
      part[th][c2] = acc0;
      part[th][c2 + 1] = acc1;
    }
    __syncthreads();
    if (tid < 128) {
      float s = part[0][tid];
      #pragma unroll
      for (int i = 1; i < 8; ++i) s += part[i][tid];
      u_s[tid] = s;
      u_s[128 + tid] = h_s[tid];
    }
    __syncthreads();
    if (tid < 384) {
      const int j = tid;
      float gxv = dbih[j], ghv = dbhh[j];
      const float* wxr = &dwih[(size_t)j * 256];
      const float* whr = &dwhh[(size_t)j * 128];
      #pragma unroll 8
      for (int k4 = 0; k4 < 64; ++k4) {
        const float4 uv = *(const float4*)&u_s[k4 * 4];
        const float4 wv = *(const float4*)&wxr[k4 * 4];
        gxv += uv.x * wv.x + uv.y * wv.y + uv.z * wv.z + uv.w * wv.w;
      }
      #pragma unroll 8
      for (int k4 = 0; k4 < 32; ++k4) {
        const float4 hv = *(const float4*)&h_s[k4 * 4];
        const float4 wv = *(const float4*)&whr[k4 * 4];
        ghv += hv.x * wv.x + hv.y * wv.y + hv.z * wv.z + hv.w * wv.w;
      }
      gx_s[j] = gxv; gh_s[j] = ghv;
    }
    __syncthreads();
    if (tid < 128) {
      const float r = fsig(gx_s[tid] + gh_s[tid]);
      const float z = fsig(gx_s[128 + tid] + gh_s[128 + tid]);
      const float n = ftanh(gx_s[256 + tid] + r * gh_s[256 + tid]);
      const float hn = (1.0f - z) * n + z * h_s[tid];
      h_s[tid] = hn;
      float s1 = hn, s2 = hn * hn;
      #pragma unroll
      for (int o = 32; o; o >>= 1) { s1 += __shfl_xor(s1, o, 64); s2 += __shfl_xor(s2, o, 64); }
      if ((tid & 63) == 0) { red[tid >> 6] = s1; red[4 + (tid >> 6)] = s2; }
    }
    __syncthreads();
    if (tid < 128) {
      const float hn  = h_s[tid];
      const float mu  = (red[0] + red[1]) * (1.0f / 128.0f);
      const float var = (red[4] + red[5]) * (1.0f / 128.0f) - mu * mu;
      y_s[tid] = (hn - mu) / sqrtf(var + 1e-5f) * lng[tid] + lnb[tid];
    }
    __syncthreads();
    if (tid < 64) {
      float acc = b1[tid];
      const float* wr = &w1[(size_t)tid * 128];
      #pragma unroll 8
      for (int k4 = 0; k4 < 32; ++k4) {
        const float4 yv = *(const float4*)&y_s[k4 * 4];
        const float4 wv = *(const float4*)&wr[k4 * 4];
        acc += yv.x * wv.x + yv.y * wv.y + yv.z * wv.z + yv.w * wv.w;
      }
      acc = fmaxf(acc, 0.0f);
      float v = acc * w2[tid];
      #pragma unroll
      for (int o = 32; o; o >>= 1) v += __shfl_xor(v, o, 64);
      if (tid == 0) out[(size_t)b * NSTEP + step] = v + b2[0];
    }
    __syncthreads();
  }
}

// -------------------------------------------------------------------------
extern "C" void kernel_launch(void* const* d_in, const int* in_sizes, int n_in,
                              void* d_out, int out_size, void* d_ws, size_t ws_size,
                              hipStream_t stream)
{
  (void)in_sizes; (void)n_in; (void)out_size; (void)ws_size;
  const float* x    = (const float*)d_in[0];
  const float* ewih[3] = {(const float*)d_in[1], (const float*)d_in[5], (const float*)d_in[9]};
  const float* ewhh[3] = {(const float*)d_in[2], (const float*)d_in[6], (const float*)d_in[10]};
  const float* ebih[3] = {(const float*)d_in[3], (const float*)d_in[7], (const float*)d_in[11]};
  const float* ebhh[3] = {(const float*)d_in[4], (const float*)d_in[8], (const float*)d_in[12]};
  const float* aWq  = (const float*)d_in[13];
  const float* abq  = (const float*)d_in[14];
  const float* aWk  = (const float*)d_in[15];
  const float* abk  = (const float*)d_in[16];
  const float* av   = (const float*)d_in[17];
  const float* dwih = (const float*)d_in[18];
  const float* dwhh = (const float*)d_in[19];
  const float* dbih = (const float*)d_in[20];
  const float* dbhh = (const float*)d_in[21];
  const float* lng  = (const float*)d_in[22];
  const float* lnb  = (const float*)d_in[23];
  const float* w1   = (const float*)d_in[24];
  const float* b1   = (const float*)d_in[25];
  const float* w2   = (const float*)d_in[26];
  const float* b2   = (const float*)d_in[27];

  const size_t HN = (size_t)T_LEN * B_SZ * H_DIM;               // 33,554,432 elems
  unsigned short* Hhi = (unsigned short*)d_ws;                  // 64 MiB (T,B,H)
  unsigned short* Hlo = Hhi + HN;                               // 64 MiB
  float* regionC = (float*)(Hlo + HN);                          // 128 MiB
  float* gxc     = regionC;                                     // 96 MiB
  float* h_state = regionC + 25165824;
  unsigned short* Whi = (unsigned short*)(h_state + 65536);
  unsigned short* Wlo = Whi + 122880;
  unsigned short* Khi = (unsigned short*)regionC;               // decode: 64 MiB

  prep_split<<<dim3(480), dim3(256), 0, stream>>>(ewih[0], ewih[1], ewih[2], Whi, Wlo);

  const int koff[3] = {0, 24576, 73728};
  const int kdim[3] = {64, 128, 128};
  for (int l = 0; l < 3; ++l) {
    for (int c = 0; c < 4; ++c) {
      const int t0 = c * T_CHUNK;
      gx_gemm<<<dim3(512, 3), dim3(256), 0, stream>>>(
          x, Hhi, Hlo, Whi + koff[l], Wlo + koff[l], ebih[l],
          gxc, t0, kdim[l], (l == 0) ? 1 : 0);
      rec_mfma<<<dim3(256), dim3(512), 0, stream>>>(
          gxc, ewhh[l], ebhh[l], Hhi, Hlo, h_state, t0, (c == 0) ? 1 : 0);
    }
  }

  keys_gemm<<<dim3(4096), dim3(256), 0, stream>>>(Hhi, Hlo, aWk, abk, Khi);
  decoder<<<dim3(512), dim3(512), 0, stream>>>(
      Hhi, Hlo, Khi, aWq, abq, av, dwih, dwhh, dbih, dbhh,
      lng, lnb, w1, b1, w2, b2, (float*)d_out);
}